// Round 1
// baseline (380.097 us; speedup 1.0000x reference)
//
#include <hip/hip_runtime.h>
#include <hip/hip_bf16.h>

// Causal self-attention, B=8 T=1024 C=1024 H=16 D=64, fp32 in/out.
// Pipeline: cast->bf16 | QKV gemm (MFMA) | flash attn (MFMA) | proj gemm (MFMA).
// ws layout (bytes): [0,16M) x_bf16 (reused as y_bf16), [16M,24M) weights bf16,
// [24M,72M) K/Q/V bf16 in [B,H,T,D]. Requires ws_size >= 72MB.

typedef __attribute__((ext_vector_type(8))) short short8;
typedef __attribute__((ext_vector_type(8))) unsigned short ushort8;
typedef __attribute__((ext_vector_type(4))) float floatx4;

#define LOG2E 1.44269504088896f

__device__ __forceinline__ unsigned short f2bf(float f) {
  unsigned int u = __float_as_uint(f);
  u += 0x7FFFu + ((u >> 16) & 1u);   // RNE
  return (unsigned short)(u >> 16);
}

__device__ __forceinline__ void gload_lds16(const void* g, void* l) {
  __builtin_amdgcn_global_load_lds(
      (const __attribute__((address_space(1))) unsigned int*)g,
      (__attribute__((address_space(3))) unsigned int*)l, 16, 0, 0);
}

// ---------------- cast fp32 -> bf16, 8 elems/thread ----------------
__global__ __launch_bounds__(256) void cast_bf16_kernel(
    const float* __restrict__ in, unsigned short* __restrict__ out, int n8) {
  int idx = blockIdx.x * 256 + threadIdx.x;
  int stride = gridDim.x * 256;
  for (int i = idx; i < n8; i += stride) {
    const float4* p = reinterpret_cast<const float4*>(in + (size_t)i * 8);
    float4 a = p[0], b = p[1];
    ushort8 r;
    r[0] = f2bf(a.x); r[1] = f2bf(a.y); r[2] = f2bf(a.z); r[3] = f2bf(a.w);
    r[4] = f2bf(b.x); r[5] = f2bf(b.y); r[6] = f2bf(b.z); r[7] = f2bf(b.w);
    *reinterpret_cast<ushort8*>(out + (size_t)i * 8) = r;
  }
}

// ---------------- bf16 GEMM: C[m,n] = sum_k A[m,k]*B[n,k] ----------------
// MODE 0: A=x_bf16[8192x1024], B=weight z (Wk/Wq/Wv), out -> kqv bf16 [B,H,T,D]
// MODE 1: A=y_bf16 [8192x1024], B=Wp, out -> fp32 [8192x1024] + bias
template <int MODE>
__global__ __launch_bounds__(256) void gemm_kernel(
    const unsigned short* __restrict__ A, const unsigned short* __restrict__ Bbase,
    unsigned short* __restrict__ outb, float* __restrict__ outf,
    const float* __restrict__ bias) {
  const int tid = threadIdx.x;
  const int lane = tid & 63;
  const int w = tid >> 6;
  const int wr = w >> 1, wc = w & 1;
  const int g = lane >> 4, r = lane & 15;
  const int m0 = blockIdx.y * 128;
  const int n0 = blockIdx.x * 128;

  const unsigned short* Bw =
      (MODE == 0) ? (Bbase + (size_t)blockIdx.z * 1048576) : Bbase;

  __shared__ unsigned short sA[128 * 32];
  __shared__ unsigned short sB[128 * 32];

  floatx4 acc[4][4];
#pragma unroll
  for (int i = 0; i < 4; ++i)
#pragma unroll
    for (int j = 0; j < 4; ++j) acc[i][j] = (floatx4)0.0f;

  for (int kt = 0; kt < 32; ++kt) {
    __syncthreads();  // previous iteration's frag reads complete
#pragma unroll
    for (int c = 0; c < 2; ++c) {
      int ci = tid + c * 256;       // 16B chunk id 0..511
      int row = ci >> 2;            // 0..127
      int colb = (ci & 3) * 16;     // byte within 64B (=BK) row
      const char* gA = (const char*)A + (size_t)(m0 + row) * 2048 + (size_t)kt * 64 + colb;
      gload_lds16(gA, &sA[(w * 64 + c * 256) * 8]);
      const char* gB = (const char*)Bw + (size_t)(n0 + row) * 2048 + (size_t)kt * 64 + colb;
      gload_lds16(gB, &sB[(w * 64 + c * 256) * 8]);
    }
    __syncthreads();  // staging done (vmcnt(0) drained by syncthreads)

    short8 aF[4], bF[4];
#pragma unroll
    for (int mf = 0; mf < 4; ++mf)
      aF[mf] = *reinterpret_cast<const short8*>(&sA[(wr * 64 + mf * 16 + r) * 32 + g * 8]);
#pragma unroll
    for (int nf = 0; nf < 4; ++nf)
      bF[nf] = *reinterpret_cast<const short8*>(&sB[(wc * 64 + nf * 16 + r) * 32 + g * 8]);
#pragma unroll
    for (int mf = 0; mf < 4; ++mf)
#pragma unroll
      for (int nf = 0; nf < 4; ++nf)
        acc[mf][nf] = __builtin_amdgcn_mfma_f32_16x16x32_bf16(aF[mf], bF[nf], acc[mf][nf], 0, 0, 0);
  }

  if (MODE == 0) {
    unsigned short* outz = outb + (size_t)blockIdx.z * 8388608;
#pragma unroll
    for (int mf = 0; mf < 4; ++mf)
#pragma unroll
      for (int nf = 0; nf < 4; ++nf)
#pragma unroll
        for (int q = 0; q < 4; ++q) {
          int m = m0 + wr * 64 + mf * 16 + g * 4 + q;   // row = b*1024+t
          int n = n0 + wc * 64 + nf * 16 + r;           // col = h*64+d
          int b = m >> 10, t = m & 1023, h = n >> 6, d = n & 63;
          outz[(size_t)((b * 16 + h) * 1024 + t) * 64 + d] = f2bf(acc[mf][nf][q]);
        }
  } else {
#pragma unroll
    for (int mf = 0; mf < 4; ++mf)
#pragma unroll
      for (int nf = 0; nf < 4; ++nf) {
        int n = n0 + wc * 64 + nf * 16 + r;
        float bv = bias[n];
#pragma unroll
        for (int q = 0; q < 4; ++q) {
          int m = m0 + wr * 64 + mf * 16 + g * 4 + q;
          outf[(size_t)m * 1024 + n] = acc[mf][nf][q] + bv;
        }
      }
  }
}

// ---------------- flash attention ----------------
// Reference computes att = (K @ Q^T) * D^-0.5, tril mask, softmax over j,
// Y = att @ V.  So "query" rows are K rows.  Per block: one (b,h), 64 i-rows,
// 4 waves x 16 rows; loop over 64-wide j-tiles (0..i-tile, causal).
__global__ __launch_bounds__(256) void attn_kernel(
    const unsigned short* __restrict__ kqv, unsigned short* __restrict__ y) {
  const int tid = threadIdx.x;
  const int lane = tid & 63;
  const int w = tid >> 6;
  const int g = lane >> 4, r = lane & 15;
  const int bh = blockIdx.y;
  const int it = blockIdx.x;
  const int i0 = it * 64;

  const unsigned short* Kh = kqv + (size_t)bh * 65536;
  const unsigned short* Qh = kqv + 8388608u + (size_t)bh * 65536;
  const unsigned short* Vh = kqv + 16777216u + (size_t)bh * 65536;

  __shared__ unsigned short Vt[64 * 80];  // [d][j], stride 80 (160B: aligned b128, bank-floor)
  __shared__ unsigned short Pl[64 * 80];  // [i][j], stride 80

  // K A-frags: rows i0 + w*16 + r, k = d (two 32-wide steps)
  short8 aK[2];
#pragma unroll
  for (int s = 0; s < 2; ++s)
    aK[s] = *reinterpret_cast<const short8*>(&Kh[(size_t)(i0 + w * 16 + r) * 64 + s * 32 + g * 8]);

  floatx4 accY[4];
#pragma unroll
  for (int dt = 0; dt < 4; ++dt) accY[dt] = (floatx4)0.0f;
  float m_run[4], l_run[4];
#pragma unroll
  for (int q = 0; q < 4; ++q) { m_run[q] = -1e30f; l_run[q] = 0.0f; }

  for (int jt = 0; jt <= it; ++jt) {
    int j0 = jt * 64;
    __syncthreads();  // prev iteration's PV reads of Vt done
    // stage V-tile transposed into LDS: thread (j = tid&63, db = tid>>6)
    {
      int j = tid & 63, db = tid >> 6;
#pragma unroll
      for (int half = 0; half < 2; ++half) {
        short8 v = *reinterpret_cast<const short8*>(&Vh[(size_t)(j0 + j) * 64 + db * 16 + half * 8]);
#pragma unroll
        for (int e = 0; e < 8; ++e)
          Vt[(db * 16 + half * 8 + e) * 80 + j] = (unsigned short)v[e];
      }
    }
    // Q B-frags (cols j of S): rows j0 + jf*16 + r of Q
    short8 bQ[4][2];
#pragma unroll
    for (int jf = 0; jf < 4; ++jf)
#pragma unroll
      for (int s = 0; s < 2; ++s)
        bQ[jf][s] = *reinterpret_cast<const short8*>(&Qh[(size_t)(j0 + jf * 16 + r) * 64 + s * 32 + g * 8]);
    // S = K.Q^T  (rows i, cols j)
    floatx4 sf[4];
#pragma unroll
    for (int jf = 0; jf < 4; ++jf) {
      sf[jf] = (floatx4)0.0f;
#pragma unroll
      for (int s = 0; s < 2; ++s)
        sf[jf] = __builtin_amdgcn_mfma_f32_16x16x32_bf16(aK[s], bQ[jf][s], sf[jf], 0, 0, 0);
    }
    // scale + causal mask (only diagonal tile)
    bool diag = (jt == it);
#pragma unroll
    for (int jf = 0; jf < 4; ++jf)
#pragma unroll
      for (int q = 0; q < 4; ++q) {
        float v = sf[jf][q] * 0.125f;
        if (diag) {
          int i = i0 + w * 16 + g * 4 + q;
          int j = j0 + jf * 16 + r;
          if (j > i) v = -1e30f;
        }
        sf[jf][q] = v;
      }
    // row max across 4 j-frags + 16 lanes of the row group
    float corr[4];
#pragma unroll
    for (int q = 0; q < 4; ++q) {
      float v = fmaxf(fmaxf(sf[0][q], sf[1][q]), fmaxf(sf[2][q], sf[3][q]));
      v = fmaxf(v, __shfl_xor(v, 1));
      v = fmaxf(v, __shfl_xor(v, 2));
      v = fmaxf(v, __shfl_xor(v, 4));
      v = fmaxf(v, __shfl_xor(v, 8));
      float mnew = fmaxf(m_run[q], v);
      corr[q] = exp2f((m_run[q] - mnew) * LOG2E);
      m_run[q] = mnew;
      l_run[q] *= corr[q];
    }
#pragma unroll
    for (int dt = 0; dt < 4; ++dt)
#pragma unroll
      for (int q = 0; q < 4; ++q) accY[dt][q] *= corr[q];
    // P = exp(S - m): row sums + bf16 into LDS (own wave's 16 rows)
    float rsum[4] = {0.f, 0.f, 0.f, 0.f};
#pragma unroll
    for (int jf = 0; jf < 4; ++jf)
#pragma unroll
      for (int q = 0; q < 4; ++q) {
        float p = exp2f((sf[jf][q] - m_run[q]) * LOG2E);
        rsum[q] += p;
        Pl[(w * 16 + g * 4 + q) * 80 + jf * 16 + r] = f2bf(p);
      }
#pragma unroll
    for (int q = 0; q < 4; ++q) {
      float v = rsum[q];
      v += __shfl_xor(v, 1);
      v += __shfl_xor(v, 2);
      v += __shfl_xor(v, 4);
      v += __shfl_xor(v, 8);
      l_run[q] += v;
    }
    __syncthreads();  // Vt staged + P written, ready for PV
    // PV: Y[i,d] += sum_j P[i,j] * V[j,d]
    short8 aP[2];
#pragma unroll
    for (int s = 0; s < 2; ++s)
      aP[s] = *reinterpret_cast<const short8*>(&Pl[(w * 16 + r) * 80 + s * 32 + g * 8]);
#pragma unroll
    for (int dt = 0; dt < 4; ++dt) {
      short8 bV[2];
#pragma unroll
      for (int s = 0; s < 2; ++s)
        bV[s] = *reinterpret_cast<const short8*>(&Vt[(dt * 16 + r) * 80 + s * 32 + g * 8]);
#pragma unroll
      for (int s = 0; s < 2; ++s)
        accY[dt] = __builtin_amdgcn_mfma_f32_16x16x32_bf16(aP[s], bV[s], accY[dt], 0, 0, 0);
    }
  }
  // epilogue: y[b, t=i, h*64+d] = accY / l
  int b = bh >> 4, h = bh & 15;
#pragma unroll
  for (int dt = 0; dt < 4; ++dt)
#pragma unroll
    for (int q = 0; q < 4; ++q) {
      int i = i0 + w * 16 + g * 4 + q;
      int c = h * 64 + dt * 16 + r;
      y[(size_t)(b * 1024 + i) * 1024 + c] = f2bf(accY[dt][q] / l_run[q]);
    }
}

extern "C" void kernel_launch(void* const* d_in, const int* in_sizes, int n_in,
                              void* d_out, int out_size, void* d_ws, size_t ws_size,
                              hipStream_t stream) {
  const float* x  = (const float*)d_in[0];
  const float* Wk = (const float*)d_in[1];
  const float* Wq = (const float*)d_in[2];
  const float* Wv = (const float*)d_in[3];
  const float* Wp = (const float*)d_in[4];
  const float* bp = (const float*)d_in[5];
  float* out = (float*)d_out;

  char* ws = (char*)d_ws;
  unsigned short* xb  = (unsigned short*)ws;                  // 8M elems (then reused as y)
  unsigned short* wb  = (unsigned short*)(ws + (16u << 20));  // 4 x 1M elems: Wk,Wq,Wv,Wp
  unsigned short* kqv = (unsigned short*)(ws + (24u << 20));  // 3 x 8M elems: K,Q,V [B,H,T,D]

  cast_bf16_kernel<<<2048, 256, 0, stream>>>(x, xb, 1048576);
  cast_bf16_kernel<<<512, 256, 0, stream>>>(Wk, wb + 0 * 1048576, 131072);
  cast_bf16_kernel<<<512, 256, 0, stream>>>(Wq, wb + 1 * 1048576, 131072);
  cast_bf16_kernel<<<512, 256, 0, stream>>>(Wv, wb + 2 * 1048576, 131072);
  cast_bf16_kernel<<<512, 256, 0, stream>>>(Wp, wb + 3 * 1048576, 131072);

  dim3 gqkv(8, 64, 3);  // (N/128, M/128, 3 weights)
  gemm_kernel<0><<<gqkv, 256, 0, stream>>>(xb, wb, kqv, nullptr, nullptr);

  attn_kernel<<<dim3(16, 128), 256, 0, stream>>>(kqv, xb /* y_bf16, reuses x region */);

  gemm_kernel<1><<<dim3(8, 64, 1), 256, 0, stream>>>(xb, wb + 3 * 1048576, nullptr, out, bp);
}